// Round 5
// baseline (166.111 us; speedup 1.0000x reference)
//
#include <hip/hip_runtime.h>
#include <math.h>

#define N_PTS 2048
#define M_PTS 128
#define INNF  256
#define H     128

#define MIN_STDC 0.30235680f   /* 0.32*1.88973/2 */
#define MAX_STDC 2.19208680f   /* 2.32*1.88973/2 */
#define PI_F     3.14159265358979f
#define LOG2E_F  1.44269504089f

static __device__ __forceinline__ float silu_f(float x) {
  return x / (1.0f + __expf(-x));
}

// ---------------------------------------------------------------------------
// K1: hpre = silu(h @ W_pre + b_pre), then
//     hdg4[n][w][l] = (hpre @ W_down[l])[n,w] * gw[n] * coef(w) / sqrt(2l+1)
// 4 n-rows per block, 256 threads (w = t&127, nh = t>>7 covers 2 n each).
// ---------------------------------------------------------------------------
__global__ __launch_bounds__(256) void k_pre(const float* __restrict__ h,
    const float* __restrict__ W_pre, const float* __restrict__ b_pre,
    const float* __restrict__ W_down, const float* __restrict__ gw,
    float* __restrict__ hdg4) {
  __shared__ float h_lds[4 * INNF];    // [n_loc][u]
  __shared__ float hp_lds[4 * H];      // [n_loc][u]
  int t = threadIdx.x;
  int n0 = blockIdx.x * 4;
  int w  = t & 127;
  int nh = t >> 7;

  // stage h rows (coalesced float4)
  {
    int row = t >> 6, col = (t & 63) << 2;
    float4 v = *(const float4*)(h + (size_t)(n0 + row) * INNF + col);
    *(float4*)&h_lds[row * INNF + col] = v;
  }
  __syncthreads();

  // stage 1: hpre rows n_loc = nh*2 + {0,1}; unroll 8 for load ILP
  float acc[2] = {0.0f, 0.0f};
  for (int u = 0; u < INNF; u += 8) {
    float4 a0a = *(const float4*)&h_lds[(nh*2 + 0) * INNF + u];
    float4 a0b = *(const float4*)&h_lds[(nh*2 + 0) * INNF + u + 4];
    float4 a1a = *(const float4*)&h_lds[(nh*2 + 1) * INNF + u];
    float4 a1b = *(const float4*)&h_lds[(nh*2 + 1) * INNF + u + 4];
    float wv[8];
    #pragma unroll
    for (int i = 0; i < 8; ++i) wv[i] = W_pre[(u + i)*H + w];
    acc[0] += a0a.x*wv[0] + a0a.y*wv[1] + a0a.z*wv[2] + a0a.w*wv[3]
            + a0b.x*wv[4] + a0b.y*wv[5] + a0b.z*wv[6] + a0b.w*wv[7];
    acc[1] += a1a.x*wv[0] + a1a.y*wv[1] + a1a.z*wv[2] + a1a.w*wv[3]
            + a1b.x*wv[4] + a1b.y*wv[5] + a1b.z*wv[6] + a1b.w*wv[7];
  }
  float bb = b_pre[w];
  hp_lds[(nh*2 + 0)*H + w] = silu_f(acc[0] + bb);
  hp_lds[(nh*2 + 1)*H + w] = silu_f(acc[1] + bb);
  __syncthreads();

  // per-w folded radial coefficient
  const float stp = (MAX_STDC - MIN_STDC) / 127.0f;
  float s = MIN_STDC + (float)w * stp;
  float temps = 2.0f * s * s;
  float coef = (2.0f/3.0f) / (temps * powf(PI_F * temps, 1.5f));
  float gwv[2] = {gw[n0 + nh*2], gw[n0 + nh*2 + 1]};
  const float invn1 = 0.57735026919f, invn2 = 0.44721359550f;

  // stage 2: 3 l's x 2 n's (12 independent weight loads per u-chunk)
  float a2[3][2] = {};
  for (int u = 0; u < H; u += 4) {
    float4 p0 = *(const float4*)&hp_lds[(nh*2 + 0)*H + u];
    float4 p1 = *(const float4*)&hp_lds[(nh*2 + 1)*H + u];
    #pragma unroll
    for (int l = 0; l < 3; ++l) {
      float w0 = W_down[((size_t)l*H + u + 0)*H + w];
      float w1 = W_down[((size_t)l*H + u + 1)*H + w];
      float w2 = W_down[((size_t)l*H + u + 2)*H + w];
      float w3 = W_down[((size_t)l*H + u + 3)*H + w];
      a2[l][0] += p0.x*w0 + p0.y*w1 + p0.z*w2 + p0.w*w3;
      a2[l][1] += p1.x*w0 + p1.y*w1 + p1.z*w2 + p1.w*w3;
    }
  }
  #pragma unroll
  for (int r = 0; r < 2; ++r) {
    float sc = gwv[r] * coef;
    size_t base = ((size_t)(n0 + nh*2 + r) * H + w) * 4;
    hdg4[base + 0] = a2[0][r]*sc;            // l=0
    hdg4[base + 1] = a2[1][r]*sc*invn1;      // l=1
    hdg4[base + 2] = a2[2][r]*sc*invn2;      // l=2
    hdg4[base + 3] = 0.0f;
  }
}

// ---------------------------------------------------------------------------
// K2: pair loop ("down"). SH tile computed in LDS; lane = w; 256 threads
// (nh = t>>7 splits the 64-n chunk), m-tile 4, grid (32 mg, 32 s).
// ---------------------------------------------------------------------------
__global__ __launch_bounds__(256) void k_down(const float* __restrict__ gc,
    const float* __restrict__ cc, const float* __restrict__ hdg4,
    float* __restrict__ c_part) {
  __shared__ float lds[4608];   // SH tile 64n*4m*12 = 3072f; reduce reuses 4608f
  int t = threadIdx.x;
  int m0 = blockIdx.x * 4;
  int ss = blockIdx.y;          // 0..31
  int n0 = ss * 64;
  int w  = t & 127;
  int nh = t >> 7;

  // phase 0: each thread computes one (n_loc, m_loc) pair's SH into LDS
  {
    int n_loc = t >> 2, m_loc = t & 3;
    int n = n0 + n_loc, m = m0 + m_loc;
    float dx = gc[3*n]   - cc[3*m];
    float dy = gc[3*n+1] - cc[3*m+1];
    float dz = gc[3*n+2] - cc[3*m+2];
    float d2 = dx*dx + dy*dy + dz*dz + 3e-20f;
    float inv = rsqrtf(d2);
    float x = dx*inv, y = dy*inv, z = dz*inv;
    const float s3 = 1.73205080757f;
    float* dst = &lds[(size_t)t * 12];
    dst[0] = 1.0f; dst[1] = x; dst[2] = y; dst[3] = z;
    dst[4] = s3*x*z; dst[5] = s3*x*y; dst[6] = y*y - 0.5f*(x*x + z*z);
    dst[7] = s3*y*z; dst[8] = 0.5f*s3*(z*z - x*x);
    dst[9] = d2; dst[10] = 0.0f; dst[11] = 0.0f;
  }
  __syncthreads();

  const float stp = (MAX_STDC - MIN_STDC) / 127.0f;
  float sw = MIN_STDC + (float)w * stp;
  float nl2t = LOG2E_F / (2.0f * sw * sw);

  float acc[4][9] = {};
  for (int j = 0; j < 32; j += 4) {
    // batch 4 hdg4 loads ahead of compute
    float4 hv[4];
    #pragma unroll
    for (int q = 0; q < 4; ++q)
      hv[q] = *(const float4*)(hdg4 + ((size_t)(n0 + nh*32 + j + q)*H + w)*4);
    #pragma unroll
    for (int q = 0; q < 4; ++q) {
      const float* shb = &lds[(size_t)(nh*32 + j + q) * 48];
      #pragma unroll
      for (int mm = 0; mm < 4; ++mm) {
        float4 q0 = *(const float4*)(shb + mm*12);
        float4 q1 = *(const float4*)(shb + mm*12 + 4);
        float4 q2 = *(const float4*)(shb + mm*12 + 8);
        float e  = exp2f(-q2.y * nl2t);
        float rp = e * q2.y;
        float t0 = hv[q].x*rp, t1 = hv[q].y*rp, t2 = hv[q].z*rp;
        acc[mm][0] += t0;
        acc[mm][1] += t1*q0.y; acc[mm][2] += t1*q0.z; acc[mm][3] += t1*q0.w;
        acc[mm][4] += t2*q1.x; acc[mm][5] += t2*q1.y;
        acc[mm][6] += t2*q1.z; acc[mm][7] += t2*q1.w;
        acc[mm][8] += t2*q2.x;
      }
    }
  }

  // cross-nh reduce via LDS, then store
  __syncthreads();
  if (nh == 1) {
    #pragma unroll
    for (int mm = 0; mm < 4; ++mm)
      #pragma unroll
      for (int li = 0; li < 9; ++li)
        lds[(mm*9 + li)*128 + w] = acc[mm][li];
  }
  __syncthreads();
  if (nh == 0) {
    #pragma unroll
    for (int mm = 0; mm < 4; ++mm)
      #pragma unroll
      for (int li = 0; li < 9; ++li) {
        float v = acc[mm][li] + lds[(mm*9 + li)*128 + w];
        c_part[(((size_t)ss*M_PTS + m0 + mm)*9 + li)*H + w] = v;
      }
  }
}

// ---------------------------------------------------------------------------
// K3: per-m: reduce 32 s-partials, apply W_up + up-norm -> CU9[m][9][w]
// (no zero rows; k_up consumes K=9 per m directly).
// ---------------------------------------------------------------------------
__global__ __launch_bounds__(256) void k_cu(const float* __restrict__ c_part,
    const float* __restrict__ W_up, float* __restrict__ CU9) {
  __shared__ float c_lds[H * 12];      // [u][li] (li 9..11 unused)
  __shared__ float red[9 * H];
  int t = threadIdx.x, m = blockIdx.x;
  int w = t & 127, uh = t >> 7;

  for (int idx = t; idx < 9 * H; idx += 256) {
    int li = idx >> 7, u = idx & 127;
    float v = 0.0f;
    #pragma unroll 8
    for (int s = 0; s < 32; ++s)
      v += c_part[(((size_t)s*M_PTS + m)*9 + li)*H + u];
    c_lds[u*12 + li] = v;
  }
  __syncthreads();

  float acc[9] = {};
  for (int u = uh*64; u < uh*64 + 64; ++u) {
    float4 q0 = *(const float4*)&c_lds[u*12];
    float4 q1 = *(const float4*)&c_lds[u*12 + 4];
    float  q8 = c_lds[u*12 + 8];
    float w0 = W_up[((size_t)0*H + u)*H + w];
    float w1 = W_up[((size_t)1*H + u)*H + w];
    float w2 = W_up[((size_t)2*H + u)*H + w];
    acc[0] += q0.x*w0;
    acc[1] += q0.y*w1; acc[2] += q0.z*w1; acc[3] += q0.w*w1;
    acc[4] += q1.x*w2; acc[5] += q1.y*w2; acc[6] += q1.z*w2;
    acc[7] += q1.w*w2; acc[8] += q8*w2;
  }
  __syncthreads();
  if (uh == 1) {
    #pragma unroll
    for (int li = 0; li < 9; ++li) red[li*128 + w] = acc[li];
  }
  __syncthreads();
  if (uh == 0) {
    const float invn[3] = {1.0f, 0.57735026919f, 0.44721359550f};
    #pragma unroll
    for (int li = 0; li < 9; ++li) {
      int l = (li == 0) ? 0 : (li < 4 ? 1 : 2);
      CU9[((size_t)m*9 + li)*H + w] = (acc[li] + red[li*128 + w]) * invn[l];
    }
  }
}

// ---------------------------------------------------------------------------
// K4: up contraction with in-kernel SH recompute.
// out[n,w] = sum_m sum_li sh[n,m,li] * CU9[m,li,w]
// Block: 32 n x 128 w, 256 threads, thread tile 2n x 8w.
// Split over m: ks covers 8 m's in two 4-m chunks (K=36 each).
// grid (64, 16) = 1024 blocks -> 4 waves/SIMD.
// ---------------------------------------------------------------------------
__global__ __launch_bounds__(256) void k_up(const float* __restrict__ gc,
    const float* __restrict__ cc, const float* __restrict__ CU9,
    float* __restrict__ out_part) {
  __shared__ float At[36 * 34];   // [k][n] pad 34 (even: aligned float2 reads)
  __shared__ float Bl[36 * 128];  // [k][w]
  int t = threadIdx.x;
  int n0 = blockIdx.x * 32;
  int ks = blockIdx.y;            // 0..15
  int tgn = t >> 4;               // 0..15 -> n_loc = 2*tgn + r
  int w0 = (t & 15) * 8;
  float acc[2][8] = {};

  for (int ch = 0; ch < 2; ++ch) {
    int m0 = ks*8 + ch*4;
    __syncthreads();              // protect LDS reuse across chunks
    if (t < 128) {                // compute SH fragment straight into At
      int n_loc = t >> 2, m_loc = t & 3;
      int n = n0 + n_loc, m = m0 + m_loc;
      float dx = gc[3*n]   - cc[3*m];
      float dy = gc[3*n+1] - cc[3*m+1];
      float dz = gc[3*n+2] - cc[3*m+2];
      float d2 = dx*dx + dy*dy + dz*dz + 3e-20f;
      float inv = rsqrtf(d2);
      float x = dx*inv, y = dy*inv, z = dz*inv;
      const float s3 = 1.73205080757f;
      float sh[9];
      sh[0] = 1.0f; sh[1] = x; sh[2] = y; sh[3] = z;
      sh[4] = s3*x*z; sh[5] = s3*x*y; sh[6] = y*y - 0.5f*(x*x + z*z);
      sh[7] = s3*y*z; sh[8] = 0.5f*s3*(z*z - x*x);
      #pragma unroll
      for (int li = 0; li < 9; ++li)
        At[(m_loc*9 + li)*34 + n_loc] = sh[li];
    }
    // stage B: contiguous 36x128 copy from CU9[m0*9 ...]
    #pragma unroll
    for (int i = 0; i < 5; ++i) {
      int idx = t + i*256;        // float4 index, 1152 total
      if (idx < 1152)
        *(float4*)&Bl[idx*4] = *(const float4*)(CU9 + ((size_t)m0*9)*H + idx*4);
    }
    __syncthreads();
    #pragma unroll 6
    for (int k = 0; k < 36; ++k) {
      float2 a = *(const float2*)&At[k*34 + 2*tgn];
      float4 b0 = *(const float4*)&Bl[k*128 + w0];
      float4 b1 = *(const float4*)&Bl[k*128 + w0 + 4];
      float bv[8] = {b0.x, b0.y, b0.z, b0.w, b1.x, b1.y, b1.z, b1.w};
      #pragma unroll
      for (int c = 0; c < 8; ++c) {
        acc[0][c] += a.x * bv[c];
        acc[1][c] += a.y * bv[c];
      }
    }
  }
  #pragma unroll
  for (int r = 0; r < 2; ++r) {
    size_t row = (size_t)ks*N_PTS + n0 + 2*tgn + r;
    *(float4*)(out_part + row*H + w0)     = make_float4(acc[r][0], acc[r][1], acc[r][2], acc[r][3]);
    *(float4*)(out_part + row*H + w0 + 4) = make_float4(acc[r][4], acc[r][5], acc[r][6], acc[r][7]);
  }
}

// ---------------------------------------------------------------------------
// K5: reduce 16 split-m partials, post-MLP + silu -> d_out.
// ---------------------------------------------------------------------------
__global__ __launch_bounds__(256) void k_post(const float* __restrict__ out_part,
    const float* __restrict__ W_post, const float* __restrict__ b_post,
    float* __restrict__ out) {
  __shared__ float op[4 * H];
  int t = threadIdx.x;
  int n0 = blockIdx.x * 4;
  int w = t & 127, nh = t >> 7;

  #pragma unroll
  for (int i = 0; i < 2; ++i) {
    int idx = t + i*256;                 // 0..511
    int nl = idx >> 7, ww = idx & 127;
    float v = 0.0f;
    #pragma unroll
    for (int s = 0; s < 16; ++s)
      v += out_part[((size_t)s*N_PTS + n0 + nl)*H + ww];
    op[nl*H + ww] = v;
  }
  __syncthreads();

  float acc[2] = {0.0f, 0.0f};
  for (int u = 0; u < H; u += 4) {
    float4 p0 = *(const float4*)&op[(nh*2 + 0)*H + u];
    float4 p1 = *(const float4*)&op[(nh*2 + 1)*H + u];
    float w0 = W_post[(u+0)*H + w];
    float w1 = W_post[(u+1)*H + w];
    float w2 = W_post[(u+2)*H + w];
    float w3 = W_post[(u+3)*H + w];
    acc[0] += p0.x*w0 + p0.y*w1 + p0.z*w2 + p0.w*w3;
    acc[1] += p1.x*w0 + p1.y*w1 + p1.z*w2 + p1.w*w3;
  }
  float bp = b_post[w];
  out[(size_t)(n0 + nh*2 + 0)*H + w] = silu_f(acc[0] + bp);
  out[(size_t)(n0 + nh*2 + 1)*H + w] = silu_f(acc[1] + bp);
}

// ---------------------------------------------------------------------------
extern "C" void kernel_launch(void* const* d_in, const int* in_sizes, int n_in,
                              void* d_out, int out_size, void* d_ws, size_t ws_size,
                              hipStream_t stream) {
  const float* h      = (const float*)d_in[0];
  const float* gc     = (const float*)d_in[1];
  const float* cc     = (const float*)d_in[2];
  const float* gw     = (const float*)d_in[3];
  const float* W_pre  = (const float*)d_in[4];
  const float* b_pre  = (const float*)d_in[5];
  const float* W_down = (const float*)d_in[6];
  const float* W_up   = (const float*)d_in[7];
  const float* W_post = (const float*)d_in[8];
  const float* b_post = (const float*)d_in[9];

  float* ws       = (float*)d_ws;
  float* hdg4     = ws;                     // 2048*128*4       = 1,048,576 f
  float* c_part   = hdg4 + 1048576;         // 32*128*9*128     = 4,718,592 f
  float* CU9      = c_part + 4718592;       // 128*9*128        =   147,456 f
  // out_part (16*2048*128 = 4,194,304 f) aliases c_part (dead after k_cu)
  float* out_part = c_part;
  float* out      = (float*)d_out;

  k_pre <<<512,           256, 0, stream>>>(h, W_pre, b_pre, W_down, gw, hdg4);
  k_down<<<dim3(32,32),   256, 0, stream>>>(gc, cc, hdg4, c_part);
  k_cu  <<<128,           256, 0, stream>>>(c_part, W_up, CU9);
  k_up  <<<dim3(64,16),   256, 0, stream>>>(gc, cc, CU9, out_part);
  k_post<<<512,           256, 0, stream>>>(out_part, W_post, b_post, out);
}